// Round 2
// baseline (6879.269 us; speedup 1.0000x reference)
//
#include <hip/hip_runtime.h>

#define N_USER 50000
#define N_ITEM 100000
#define N_NODES 150000
#define EMB 64
#define NNZ 2400000
#define BATCH 4096

// ---------------- init: ego = concat(user_emb, item_emb), float4 copy ----------------
__global__ __launch_bounds__(256) void init_ego(const float4* __restrict__ ue,
                                                const float4* __restrict__ ie,
                                                float4* __restrict__ ego) {
    int i = blockIdx.x * 256 + threadIdx.x;            // over N_NODES*EMB/4 = 2.4M float4
    if (i >= N_NODES * EMB / 4) return;
    const int NU4 = N_USER * EMB / 4;                  // 800k
    ego[i] = (i < NU4) ? ue[i] : ie[i - NU4];
}

// ---------------- SpMM scatter: side[row] += val * ego[col] ----------------
__global__ __launch_bounds__(256) void spmm_scatter(const int* __restrict__ rows,
                                                    const int* __restrict__ cols,
                                                    const float* __restrict__ vals,
                                                    const float* __restrict__ ego,
                                                    float* __restrict__ side) {
    int t = blockIdx.x * 256 + threadIdx.x;            // NNZ*16 threads, 4 dims each
    int e = t >> 4;
    if (e >= NNZ) return;
    int g = (t & 15) << 2;
    int r = rows[e], c = cols[e];
    float v = vals[e];
    const float4 x = *(const float4*)(ego + (size_t)c * EMB + g);
    float* dst = side + (size_t)r * EMB + g;
    atomicAdd(dst + 0, v * x.x);
    atomicAdd(dst + 1, v * x.y);
    atomicAdd(dst + 2, v * x.z);
    atomicAdd(dst + 3, v * x.w);
}

// ---- dense update: ego = leaky(side@Wgc + bgc + (ego*side)@Wbi + bbi); inv[n] = 1/max(||ego_n||,eps) ----
__global__ __launch_bounds__(256) void dense_update(float* __restrict__ ego,
                                                    const float* __restrict__ side,
                                                    const float* __restrict__ Wgc,
                                                    const float* __restrict__ bgc,
                                                    const float* __restrict__ Wbi,
                                                    const float* __restrict__ bbi,
                                                    float* __restrict__ inv_norm,
                                                    int layer) {
    const int lane = threadIdx.x & 63;
    const int node = blockIdx.x * 4 + (threadIdx.x >> 6);   // grid = 37500 → exactly 150000 nodes

    // thread `lane` holds column `lane` of Wgc and Wbi in registers (128 VGPRs)
    const float* Wg = Wgc + layer * EMB * EMB;
    const float* Wb = Wbi + layer * EMB * EMB;
    float wgc[64], wbi[64];
#pragma unroll
    for (int j = 0; j < 64; ++j) {
        wgc[j] = Wg[j * 64 + lane];                    // coalesced: lanes read contiguous 256B
        wbi[j] = Wb[j * 64 + lane];
    }

    const size_t base = (size_t)node * EMB;
    const float a = side[base + lane];
    const float e = ego[base + lane];
    const float c = e * a;
    float acc = bgc[layer * 64 + lane] + bbi[layer * 64 + lane];
#pragma unroll
    for (int j = 0; j < 64; ++j) {
        acc = fmaf(__shfl(a, j), wgc[j], acc);
        acc = fmaf(__shfl(c, j), wbi[j], acc);
    }
    float x = (acc >= 0.f) ? acc : 0.2f * acc;         // leaky_relu slope 0.2
    ego[base + lane] = x;                              // in-place: no cross-node deps

    float s = x * x;                                   // wave-64 L2 norm
#pragma unroll
    for (int off = 32; off > 0; off >>= 1) s += __shfl_xor(s, off);
    float inv = 1.0f / fmaxf(sqrtf(s), 1e-12f);
    if (lane == 0) inv_norm[node] = inv;
}

// ---- gather one 64-col slice for the 12288 sampled rows into out (row stride 256) ----
// layer 0: src_i != nullptr, reads raw embeddings; layers 1-3: inv != nullptr, reads ego*inv
__global__ __launch_bounds__(256) void gather_layer(const int* __restrict__ users,
                                                    const int* __restrict__ pos,
                                                    const int* __restrict__ neg,
                                                    const float* __restrict__ src_u,
                                                    const float* __restrict__ src_i,
                                                    const float* __restrict__ inv,
                                                    float* __restrict__ out,
                                                    int col0) {
    int t = blockIdx.x * 256 + threadIdx.x;            // 3*4096*64 threads
    if (t >= 3 * BATCH * EMB) return;
    int r = t >> 6, d = t & 63;
    int seg = r >> 12, idx = r & (BATCH - 1);
    int node = (seg == 0) ? users[idx] : N_USER + ((seg == 1) ? pos[idx] : neg[idx]);
    float v;
    if (inv) {
        v = src_u[(size_t)node * EMB + d] * inv[node];
    } else {
        v = (node < N_USER) ? src_u[(size_t)node * EMB + d]
                            : src_i[(size_t)(node - N_USER) * EMB + d];
    }
    out[(size_t)r * 256 + col0 + d] = v;
}

extern "C" void kernel_launch(void* const* d_in, const int* in_sizes, int n_in,
                              void* d_out, int out_size, void* d_ws, size_t ws_size,
                              hipStream_t stream) {
    const int* users = (const int*)d_in[0];
    const int* pos   = (const int*)d_in[1];
    const int* neg   = (const int*)d_in[2];
    const int* arow  = (const int*)d_in[3];
    const int* acol  = (const int*)d_in[4];
    const float* aval = (const float*)d_in[5];
    const float* ue   = (const float*)d_in[6];
    const float* ie   = (const float*)d_in[7];
    const float* Wgc  = (const float*)d_in[8];
    const float* bgc  = (const float*)d_in[9];
    const float* Wbi  = (const float*)d_in[10];
    const float* bbi  = (const float*)d_in[11];
    float* out = (float*)d_out;

    char* ws = (char*)d_ws;
    const size_t egoBytes = (size_t)N_NODES * EMB * sizeof(float);   // 38.4 MB
    float* ego  = (float*)ws;
    float* side = (float*)(ws + egoBytes);
    float* inv  = (float*)(ws + 2 * egoBytes);                       // 0.6 MB

    init_ego<<<(N_NODES * EMB / 4 + 255) / 256, 256, 0, stream>>>(
        (const float4*)ue, (const float4*)ie, (float4*)ego);

    // layer-0 slice of the output: raw embeddings
    gather_layer<<<(3 * BATCH * EMB) / 256, 256, 0, stream>>>(
        users, pos, neg, ue, ie, nullptr, out, 0);

    for (int k = 0; k < 3; ++k) {
        hipMemsetAsync(side, 0, egoBytes, stream);
        spmm_scatter<<<(NNZ * 16) / 256, 256, 0, stream>>>(arow, acol, aval, ego, side);
        dense_update<<<N_NODES / 4, 256, 0, stream>>>(ego, side, Wgc, bgc, Wbi, bbi, inv, k);
        gather_layer<<<(3 * BATCH * EMB) / 256, 256, 0, stream>>>(
            users, pos, neg, ego, nullptr, inv, out, (k + 1) * EMB);
    }
}

// Round 3
// 1523.307 us; speedup vs baseline: 4.5160x; 4.5160x over previous
//
#include <hip/hip_runtime.h>

#define N_USER 50000
#define N_ITEM 100000
#define N_NODES 150000
#define EMB 64
#define NNZ 2400000
#define BATCH 4096
#define SCAN_BLOCKS ((N_NODES + 255) / 256)   // 586

// ---------------- init: ego = concat(user_emb, item_emb), float4 copy ----------------
__global__ __launch_bounds__(256) void init_ego(const float4* __restrict__ ue,
                                                const float4* __restrict__ ie,
                                                float4* __restrict__ ego) {
    int i = blockIdx.x * 256 + threadIdx.x;            // over N_NODES*EMB/4 = 2.4M float4
    if (i >= N_NODES * EMB / 4) return;
    const int NU4 = N_USER * EMB / 4;
    ego[i] = (i < NU4) ? ue[i] : ie[i - NU4];
}

// ---------------- CSR build ----------------
__global__ __launch_bounds__(256) void hist(const int* __restrict__ rows, int* __restrict__ cnt) {
    int e = blockIdx.x * 256 + threadIdx.x;
    if (e < NNZ) atomicAdd(&cnt[rows[e]], 1);
}

__global__ __launch_bounds__(256) void scan_k1(const int* __restrict__ cnt,
                                               int* __restrict__ row_start,
                                               int* __restrict__ partials) {
    __shared__ int s[256];
    int t = threadIdx.x, i = blockIdx.x * 256 + t;
    int v = (i < N_NODES) ? cnt[i] : 0;
    s[t] = v;
    for (int off = 1; off < 256; off <<= 1) {
        __syncthreads();
        int add = (t >= off) ? s[t - off] : 0;
        __syncthreads();
        s[t] += add;
    }
    if (i < N_NODES) row_start[i] = s[t] - v;          // local exclusive scan
    if (t == 255) partials[blockIdx.x] = s[255];
}

__global__ __launch_bounds__(1024) void scan_k2(int* __restrict__ partials, int nb) {
    __shared__ int s[1024];
    int t = threadIdx.x;
    int v = (t < nb) ? partials[t] : 0;
    s[t] = v;
    for (int off = 1; off < 1024; off <<= 1) {
        __syncthreads();
        int add = (t >= off) ? s[t - off] : 0;
        __syncthreads();
        s[t] += add;
    }
    if (t < nb) partials[t] = s[t] - v;                // exclusive block offsets
}

__global__ __launch_bounds__(256) void scan_k3(int* __restrict__ row_start,
                                               const int* __restrict__ partials,
                                               int* __restrict__ cursor) {
    int i = blockIdx.x * 256 + threadIdx.x;
    if (i < N_NODES) {
        int v = row_start[i] + partials[blockIdx.x];
        row_start[i] = v;
        cursor[i] = v;
    }
    if (i == 0) row_start[N_NODES] = NNZ;
}

__global__ __launch_bounds__(256) void scatter_edges(const int* __restrict__ rows,
                                                     const int* __restrict__ cols,
                                                     const float* __restrict__ vals,
                                                     int* __restrict__ cursor,
                                                     int2* __restrict__ ecv) {
    int e = blockIdx.x * 256 + threadIdx.x;
    if (e >= NNZ) return;
    int pos = atomicAdd(&cursor[rows[e]], 1);
    ecv[pos] = make_int2(cols[e], __float_as_int(vals[e]));
}

// ---- fused SpMM (CSR gather-reduce) + dense transform + leaky-relu + norm ----
// one 64-lane wave per row; lane = output dim; weights staged in LDS (shared by 4 waves)
__global__ __launch_bounds__(256) void spmm_dense(const int* __restrict__ row_start,
                                                  const int2* __restrict__ ecv,
                                                  const float* __restrict__ ego_in,
                                                  float* __restrict__ ego_out,
                                                  const float* __restrict__ Wgc,
                                                  const float* __restrict__ bgc,
                                                  const float* __restrict__ Wbi,
                                                  const float* __restrict__ bbi,
                                                  float* __restrict__ inv_norm,
                                                  int layer) {
    __shared__ float lwgc[64 * 64];
    __shared__ float lwbi[64 * 64];
    const int t = threadIdx.x;
    const int lane = t & 63;
    const int node = blockIdx.x * 4 + (t >> 6);        // grid = 37500 → exactly 150000 nodes

    const float* Wg = Wgc + layer * EMB * EMB;
    const float* Wb = Wbi + layer * EMB * EMB;
    for (int idx = t; idx < 64 * 64; idx += 256) {     // cooperative 32 KB stage
        lwgc[idx] = Wg[idx];
        lwbi[idx] = Wb[idx];
    }
    __syncthreads();

    // ---- CSR segment gather-reduce: a = Σ val * ego_in[col][lane] ----
    const int s0 = row_start[node];
    const int s1 = row_start[node + 1];
    float acc0 = 0.f, acc1 = 0.f;
    for (int e0 = s0; e0 < s1; e0 += 64) {
        const int cnt = min(64, s1 - e0);
        int2 m = make_int2(0, 0);
        if (lane < cnt) m = ecv[e0 + lane];
        int j = 0;
        for (; j + 2 <= cnt; j += 2) {
            int   c0 = __shfl(m.x, j);
            int   c1 = __shfl(m.x, j + 1);
            float v0 = __int_as_float(__shfl(m.y, j));
            float v1 = __int_as_float(__shfl(m.y, j + 1));
            float x0 = ego_in[(size_t)c0 * EMB + lane];   // 256B coalesced row read
            float x1 = ego_in[(size_t)c1 * EMB + lane];
            acc0 = fmaf(v0, x0, acc0);
            acc1 = fmaf(v1, x1, acc1);
        }
        if (j < cnt) {
            int   c0 = __shfl(m.x, j);
            float v0 = __int_as_float(__shfl(m.y, j));
            acc0 = fmaf(v0, ego_in[(size_t)c0 * EMB + lane], acc0);
        }
    }
    const float a = acc0 + acc1;

    // ---- dense: leaky(side@Wgc + bgc + (ego*side)@Wbi + bbi) ----
    const size_t base = (size_t)node * EMB;
    const float e = ego_in[base + lane];
    const float ca = e * a;
    float acc = bgc[layer * 64 + lane] + bbi[layer * 64 + lane];
#pragma unroll
    for (int j = 0; j < 64; ++j) {
        acc = fmaf(__shfl(a, j), lwgc[j * 64 + lane], acc);
        acc = fmaf(__shfl(ca, j), lwbi[j * 64 + lane], acc);
    }
    float x = (acc >= 0.f) ? acc : 0.2f * acc;         // leaky_relu slope 0.2
    ego_out[base + lane] = x;

    float s = x * x;                                   // wave-64 L2 norm
#pragma unroll
    for (int off = 32; off > 0; off >>= 1) s += __shfl_xor(s, off);
    float inv = 1.0f / fmaxf(sqrtf(s), 1e-12f);
    if (lane == 0) inv_norm[node] = inv;
}

// ---- gather one 64-col slice for the 12288 sampled rows into out (row stride 256) ----
__global__ __launch_bounds__(256) void gather_layer(const int* __restrict__ users,
                                                    const int* __restrict__ pos,
                                                    const int* __restrict__ neg,
                                                    const float* __restrict__ src_u,
                                                    const float* __restrict__ src_i,
                                                    const float* __restrict__ inv,
                                                    float* __restrict__ out,
                                                    int col0) {
    int t = blockIdx.x * 256 + threadIdx.x;            // 3*4096*64 threads
    if (t >= 3 * BATCH * EMB) return;
    int r = t >> 6, d = t & 63;
    int seg = r >> 12, idx = r & (BATCH - 1);
    int node = (seg == 0) ? users[idx] : N_USER + ((seg == 1) ? pos[idx] : neg[idx]);
    float v;
    if (inv) {
        v = src_u[(size_t)node * EMB + d] * inv[node];
    } else {
        v = (node < N_USER) ? src_u[(size_t)node * EMB + d]
                            : src_i[(size_t)(node - N_USER) * EMB + d];
    }
    out[(size_t)r * 256 + col0 + d] = v;
}

extern "C" void kernel_launch(void* const* d_in, const int* in_sizes, int n_in,
                              void* d_out, int out_size, void* d_ws, size_t ws_size,
                              hipStream_t stream) {
    const int* users = (const int*)d_in[0];
    const int* pos   = (const int*)d_in[1];
    const int* neg   = (const int*)d_in[2];
    const int* arow  = (const int*)d_in[3];
    const int* acol  = (const int*)d_in[4];
    const float* aval = (const float*)d_in[5];
    const float* ue   = (const float*)d_in[6];
    const float* ie   = (const float*)d_in[7];
    const float* Wgc  = (const float*)d_in[8];
    const float* bgc  = (const float*)d_in[9];
    const float* Wbi  = (const float*)d_in[10];
    const float* bbi  = (const float*)d_in[11];
    float* out = (float*)d_out;

    char* ws = (char*)d_ws;
    const size_t egoBytes = (size_t)N_NODES * EMB * sizeof(float);   // 38,400,000 B
    float* ego_a   = (float*)(ws);
    float* ego_b   = (float*)(ws + egoBytes);
    int2*  ecv     = (int2*)(ws + 2 * egoBytes);                     // 19.2 MB
    int*   row_start = (int*)(ws + 2 * egoBytes + 19200000);         // 600 KB (+pad)
    int*   cursor    = (int*)(ws + 2 * egoBytes + 19200000 + 600064); // aliases row_cnt
    float* inv       = (float*)(ws + 2 * egoBytes + 19200000 + 2 * 600064);
    int*   partials  = (int*)(ws + 2 * egoBytes + 19200000 + 3 * 600064);

    // ---- CSR build (graph reused across all 3 layers) ----
    int* row_cnt = cursor;                              // reuse: cnt consumed before cursor written
    hipMemsetAsync(row_cnt, 0, N_NODES * sizeof(int), stream);
    hist<<<NNZ / 256, 256, 0, stream>>>(arow, row_cnt);
    scan_k1<<<SCAN_BLOCKS, 256, 0, stream>>>(row_cnt, row_start, partials);
    scan_k2<<<1, 1024, 0, stream>>>(partials, SCAN_BLOCKS);
    scan_k3<<<SCAN_BLOCKS, 256, 0, stream>>>(row_start, partials, cursor);
    scatter_edges<<<NNZ / 256, 256, 0, stream>>>(arow, acol, aval, cursor, ecv);

    // ---- embeddings ----
    init_ego<<<(N_NODES * EMB / 4 + 255) / 256, 256, 0, stream>>>(
        (const float4*)ue, (const float4*)ie, (float4*)ego_a);

    gather_layer<<<(3 * BATCH * EMB) / 256, 256, 0, stream>>>(
        users, pos, neg, ue, ie, nullptr, out, 0);

    float* bufs[2] = { ego_a, ego_b };
    for (int k = 0; k < 3; ++k) {
        float* ein  = bufs[k & 1];
        float* eout = bufs[(k + 1) & 1];
        spmm_dense<<<N_NODES / 4, 256, 0, stream>>>(
            row_start, ecv, ein, eout, Wgc, bgc, Wbi, bbi, inv, k);
        gather_layer<<<(3 * BATCH * EMB) / 256, 256, 0, stream>>>(
            users, pos, neg, eout, nullptr, inv, out, (k + 1) * EMB);
    }
}

// Round 4
// 1079.359 us; speedup vs baseline: 6.3735x; 1.4113x over previous
//
#include <hip/hip_runtime.h>

#define N_USER 50000
#define N_ITEM 100000
#define N_NODES 150000
#define EMB 64
#define NNZ 2400000
#define BATCH 4096
#define NSAMP (3 * BATCH)                     // 12288 sampled rows
#define SCAN_BLOCKS ((N_NODES + 255) / 256)   // 586

// ---------------- init: ego = concat(user_emb, item_emb), float4 copy ----------------
__global__ __launch_bounds__(256) void init_ego(const float4* __restrict__ ue,
                                                const float4* __restrict__ ie,
                                                float4* __restrict__ ego) {
    int i = blockIdx.x * 256 + threadIdx.x;
    if (i >= N_NODES * EMB / 4) return;
    const int NU4 = N_USER * EMB / 4;
    ego[i] = (i < NU4) ? ue[i] : ie[i - NU4];
}

// ---------------- CSR build ----------------
__global__ __launch_bounds__(256) void hist(const int* __restrict__ rows, int* __restrict__ cnt) {
    int e = blockIdx.x * 256 + threadIdx.x;
    if (e < NNZ) atomicAdd(&cnt[rows[e]], 1);
}

__global__ __launch_bounds__(256) void scan_k1(const int* __restrict__ cnt,
                                               int* __restrict__ row_start,
                                               int* __restrict__ partials) {
    __shared__ int s[256];
    int t = threadIdx.x, i = blockIdx.x * 256 + t;
    int v = (i < N_NODES) ? cnt[i] : 0;
    s[t] = v;
    for (int off = 1; off < 256; off <<= 1) {
        __syncthreads();
        int add = (t >= off) ? s[t - off] : 0;
        __syncthreads();
        s[t] += add;
    }
    if (i < N_NODES) row_start[i] = s[t] - v;
    if (t == 255) partials[blockIdx.x] = s[255];
}

__global__ __launch_bounds__(1024) void scan_k2(int* __restrict__ partials, int nb) {
    __shared__ int s[1024];
    int t = threadIdx.x;
    int v = (t < nb) ? partials[t] : 0;
    s[t] = v;
    for (int off = 1; off < 1024; off <<= 1) {
        __syncthreads();
        int add = (t >= off) ? s[t - off] : 0;
        __syncthreads();
        s[t] += add;
    }
    if (t < nb) partials[t] = s[t] - v;
}

__global__ __launch_bounds__(256) void scan_k3(int* __restrict__ row_start,
                                               const int* __restrict__ partials,
                                               int* __restrict__ cursor) {
    int i = blockIdx.x * 256 + threadIdx.x;
    if (i < N_NODES) {
        int v = row_start[i] + partials[blockIdx.x];
        row_start[i] = v;
        cursor[i] = v;
    }
    if (i == 0) row_start[N_NODES] = NNZ;
}

__global__ __launch_bounds__(256) void scatter_edges(const int* __restrict__ rows,
                                                     const int* __restrict__ cols,
                                                     const float* __restrict__ vals,
                                                     int* __restrict__ cursor,
                                                     int2* __restrict__ ecv) {
    int e = blockIdx.x * 256 + threadIdx.x;
    if (e >= NNZ) return;
    int pos = atomicAdd(&cursor[rows[e]], 1);
    ecv[pos] = make_int2(cols[e], __float_as_int(vals[e]));
}

// ======== core per-node compute: CSR gather-reduce (float4, 4 edges/instr) + dense ========
// returns x (per-lane output dim value, pre-norm) and inv (1/norm), both in all lanes
__device__ __forceinline__ void node_compute(int node,
                                             const int* __restrict__ row_start,
                                             const int2* __restrict__ ecv,
                                             const float* __restrict__ ego_in,
                                             const float* __restrict__ lwgc,
                                             const float* __restrict__ lwbi,
                                             const float* __restrict__ bgc,
                                             const float* __restrict__ bbi,
                                             int layer, int lane,
                                             float& x_out, float& inv_out) {
    const int j = lane >> 4;            // edge slot within quad (0..3)
    const int g = (lane & 15) << 2;     // dim offset (float4 group)
    const int s0 = row_start[node];
    const int s1 = row_start[node + 1];

    float4 acc0 = make_float4(0.f, 0.f, 0.f, 0.f);
    float4 acc1 = make_float4(0.f, 0.f, 0.f, 0.f);
    for (int e0 = s0; e0 < s1; e0 += 64) {
        const int cnt = min(64, s1 - e0);
        int2 m = make_int2(0, 0);                      // zero-fill => maskless tail
        if (lane < cnt) m = ecv[e0 + lane];
        for (int jj = 0; jj < cnt; jj += 8) {
            int   i0 = jj + j;                         // <= 63 always (jj <= 56)
            int   c0 = __shfl(m.x, i0);
            float v0 = __int_as_float(__shfl(m.y, i0));
            const float4 x0 = *(const float4*)(ego_in + (size_t)c0 * EMB + g);
            int   i1 = jj + 4 + j;
            int   c1 = __shfl(m.x, i1);
            float v1 = __int_as_float(__shfl(m.y, i1));
            const float4 x1 = *(const float4*)(ego_in + (size_t)c1 * EMB + g);
            acc0.x = fmaf(v0, x0.x, acc0.x); acc0.y = fmaf(v0, x0.y, acc0.y);
            acc0.z = fmaf(v0, x0.z, acc0.z); acc0.w = fmaf(v0, x0.w, acc0.w);
            acc1.x = fmaf(v1, x1.x, acc1.x); acc1.y = fmaf(v1, x1.y, acc1.y);
            acc1.z = fmaf(v1, x1.z, acc1.z); acc1.w = fmaf(v1, x1.w, acc1.w);
        }
    }
    // combine the two accs, then reduce across the 4 edge-slot groups (lane bits 4,5)
    float av[4] = { acc0.x + acc1.x, acc0.y + acc1.y, acc0.z + acc1.z, acc0.w + acc1.w };
#pragma unroll
    for (int c = 0; c < 4; ++c) {
        av[c] += __shfl_xor(av[c], 16);
        av[c] += __shfl_xor(av[c], 32);
    }
    // now every lane holds side[node][4*(lane&15) .. +3] in av[0..3]

    // ca = ego * side (same float4 layout)
    const size_t base = (size_t)node * EMB;
    const float4 e4 = *(const float4*)(ego_in + base + ((lane & 15) << 2));
    float cv[4] = { e4.x * av[0], e4.y * av[1], e4.z * av[2], e4.w * av[3] };

    // dense: acc[lane] = bgc+bbi + sum_j side_j * Wgc[j][lane] + (ego_j*side_j) * Wbi[j][lane]
    float acc = bgc[layer * 64 + lane] + bbi[layer * 64 + lane];
#pragma unroll
    for (int jq = 0; jq < 16; ++jq) {
#pragma unroll
        for (int c = 0; c < 4; ++c) {
            const int jd = jq * 4 + c;
            float bj = __shfl(av[c], jq);              // constant-lane after unroll
            float dj = __shfl(cv[c], jq);
            acc = fmaf(bj, lwgc[jd * 64 + lane], acc);
            acc = fmaf(dj, lwbi[jd * 64 + lane], acc);
        }
    }
    float x = (acc >= 0.f) ? acc : 0.2f * acc;         // leaky_relu 0.2

    float s = x * x;                                   // wave-64 L2 norm
#pragma unroll
    for (int off = 32; off > 0; off >>= 1) s += __shfl_xor(s, off);
    x_out = x;
    inv_out = 1.0f / fmaxf(sqrtf(s), 1e-12f);
}

// ---- full-layer fused kernel: all 150000 nodes, writes ego_out + inv_norm ----
__global__ __launch_bounds__(256) void spmm_dense(const int* __restrict__ row_start,
                                                  const int2* __restrict__ ecv,
                                                  const float* __restrict__ ego_in,
                                                  float* __restrict__ ego_out,
                                                  const float* __restrict__ Wgc,
                                                  const float* __restrict__ bgc,
                                                  const float* __restrict__ Wbi,
                                                  const float* __restrict__ bbi,
                                                  float* __restrict__ inv_norm,
                                                  int layer) {
    __shared__ float lwgc[64 * 64];
    __shared__ float lwbi[64 * 64];
    const int t = threadIdx.x;
    const int lane = t & 63;
    const int node = blockIdx.x * 4 + (t >> 6);        // grid = 37500

    const float* Wg = Wgc + layer * EMB * EMB;
    const float* Wb = Wbi + layer * EMB * EMB;
    for (int idx = t; idx < 64 * 64; idx += 256) {
        lwgc[idx] = Wg[idx];
        lwbi[idx] = Wb[idx];
    }
    __syncthreads();

    float x, inv;
    node_compute(node, row_start, ecv, ego_in, lwgc, lwbi, bgc, bbi, layer, lane, x, inv);
    ego_out[(size_t)node * EMB + lane] = x;
    if (lane == 0) inv_norm[node] = inv;
}

// ---- last-layer kernel: only the 12288 sampled rows, writes normalized slice into out ----
__global__ __launch_bounds__(256) void spmm_dense_sampled(const int* __restrict__ row_start,
                                                          const int2* __restrict__ ecv,
                                                          const float* __restrict__ ego_in,
                                                          const int* __restrict__ users,
                                                          const int* __restrict__ pos,
                                                          const int* __restrict__ neg,
                                                          const float* __restrict__ Wgc,
                                                          const float* __restrict__ bgc,
                                                          const float* __restrict__ Wbi,
                                                          const float* __restrict__ bbi,
                                                          float* __restrict__ out,
                                                          int layer) {
    __shared__ float lwgc[64 * 64];
    __shared__ float lwbi[64 * 64];
    const int t = threadIdx.x;
    const int lane = t & 63;
    const int r = blockIdx.x * 4 + (t >> 6);           // grid = 3072 -> 12288 rows

    const float* Wg = Wgc + layer * EMB * EMB;
    const float* Wb = Wbi + layer * EMB * EMB;
    for (int idx = t; idx < 64 * 64; idx += 256) {
        lwgc[idx] = Wg[idx];
        lwbi[idx] = Wb[idx];
    }
    __syncthreads();

    const int seg = r >> 12, idx = r & (BATCH - 1);
    const int node = (seg == 0) ? users[idx] : N_USER + ((seg == 1) ? pos[idx] : neg[idx]);

    float x, inv;
    node_compute(node, row_start, ecv, ego_in, lwgc, lwbi, bgc, bbi, layer, lane, x, inv);
    out[(size_t)r * 256 + (layer + 1) * 64 + lane] = x * inv;
}

// ---- gather one 64-col slice for the 12288 sampled rows into out (row stride 256) ----
__global__ __launch_bounds__(256) void gather_layer(const int* __restrict__ users,
                                                    const int* __restrict__ pos,
                                                    const int* __restrict__ neg,
                                                    const float* __restrict__ src_u,
                                                    const float* __restrict__ src_i,
                                                    const float* __restrict__ inv,
                                                    float* __restrict__ out,
                                                    int col0) {
    int t = blockIdx.x * 256 + threadIdx.x;
    if (t >= NSAMP * EMB) return;
    int r = t >> 6, d = t & 63;
    int seg = r >> 12, idx = r & (BATCH - 1);
    int node = (seg == 0) ? users[idx] : N_USER + ((seg == 1) ? pos[idx] : neg[idx]);
    float v;
    if (inv) {
        v = src_u[(size_t)node * EMB + d] * inv[node];
    } else {
        v = (node < N_USER) ? src_u[(size_t)node * EMB + d]
                            : src_i[(size_t)(node - N_USER) * EMB + d];
    }
    out[(size_t)r * 256 + col0 + d] = v;
}

extern "C" void kernel_launch(void* const* d_in, const int* in_sizes, int n_in,
                              void* d_out, int out_size, void* d_ws, size_t ws_size,
                              hipStream_t stream) {
    const int* users = (const int*)d_in[0];
    const int* pos   = (const int*)d_in[1];
    const int* neg   = (const int*)d_in[2];
    const int* arow  = (const int*)d_in[3];
    const int* acol  = (const int*)d_in[4];
    const float* aval = (const float*)d_in[5];
    const float* ue   = (const float*)d_in[6];
    const float* ie   = (const float*)d_in[7];
    const float* Wgc  = (const float*)d_in[8];
    const float* bgc  = (const float*)d_in[9];
    const float* Wbi  = (const float*)d_in[10];
    const float* bbi  = (const float*)d_in[11];
    float* out = (float*)d_out;

    char* ws = (char*)d_ws;
    const size_t egoBytes = (size_t)N_NODES * EMB * sizeof(float);   // 38,400,000 B
    float* ego_a     = (float*)(ws);
    float* ego_b     = (float*)(ws + egoBytes);
    int2*  ecv       = (int2*)(ws + 2 * egoBytes);                   // 19.2 MB
    int*   row_start = (int*)(ws + 2 * egoBytes + 19200000);         // 600 KB (+pad)
    int*   cursor    = (int*)(ws + 2 * egoBytes + 19200000 + 600064);
    float* inv       = (float*)(ws + 2 * egoBytes + 19200000 + 2 * 600064);
    int*   partials  = (int*)(ws + 2 * egoBytes + 19200000 + 3 * 600064);

    // ---- CSR build (graph reused across all 3 layers) ----
    int* row_cnt = cursor;
    hipMemsetAsync(row_cnt, 0, N_NODES * sizeof(int), stream);
    hist<<<NNZ / 256, 256, 0, stream>>>(arow, row_cnt);
    scan_k1<<<SCAN_BLOCKS, 256, 0, stream>>>(row_cnt, row_start, partials);
    scan_k2<<<1, 1024, 0, stream>>>(partials, SCAN_BLOCKS);
    scan_k3<<<SCAN_BLOCKS, 256, 0, stream>>>(row_start, partials, cursor);
    scatter_edges<<<NNZ / 256, 256, 0, stream>>>(arow, acol, aval, cursor, ecv);

    // ---- embeddings ----
    init_ego<<<(N_NODES * EMB / 4 + 255) / 256, 256, 0, stream>>>(
        (const float4*)ue, (const float4*)ie, (float4*)ego_a);

    gather_layer<<<(NSAMP * EMB) / 256, 256, 0, stream>>>(
        users, pos, neg, ue, ie, nullptr, out, 0);

    // layer 1: ego_a -> ego_b; layer 2: ego_b -> ego_a
    spmm_dense<<<N_NODES / 4, 256, 0, stream>>>(
        row_start, ecv, ego_a, ego_b, Wgc, bgc, Wbi, bbi, inv, 0);
    gather_layer<<<(NSAMP * EMB) / 256, 256, 0, stream>>>(
        users, pos, neg, ego_b, nullptr, inv, out, 64);

    spmm_dense<<<N_NODES / 4, 256, 0, stream>>>(
        row_start, ecv, ego_b, ego_a, Wgc, bgc, Wbi, bbi, inv, 1);
    gather_layer<<<(NSAMP * EMB) / 256, 256, 0, stream>>>(
        users, pos, neg, ego_a, nullptr, inv, out, 128);

    // layer 3: only the sampled rows, straight into out
    spmm_dense_sampled<<<NSAMP / 4, 256, 0, stream>>>(
        row_start, ecv, ego_a, users, pos, neg, Wgc, bgc, Wbi, bbi, out, 2);
}